// Round 11
// baseline (266.515 us; speedup 1.0000x reference)
//
#include <hip/hip_runtime.h>
#include <math.h>

#define NS 20000
#define TT 6890
#define TPAD 7168
#define FE 128
#define EDG 640000
#define DEG 32

#define RPB 160           // rows per block -> 125 row-blocks exact
#define NCB 4             // col-blocks
#define CBW 1792          // cols per col-block (TPAD/4)
#define NSTRIP 14         // 128-col strips per col-block

typedef __attribute__((ext_vector_type(8))) short short8;      // 8 bf16
typedef __attribute__((ext_vector_type(16))) float floatx16;   // 32x32 MFMA C/D
typedef unsigned int uint;

__device__ __forceinline__ unsigned short f2bf(float f) {
  unsigned int u = __float_as_uint(f);
  return (unsigned short)((u + 0x7fffu + ((u >> 16) & 1u)) >> 16);  // RNE
}

// ---------------- K0: col-major swizzled bf16 records + tn + tn256 ----------------
// Col w: 256 B at tfbx + w*128 shorts; 16B chunk jj stored at slot jj^(w&7).
__global__ void tn_cast_kernel(const float* __restrict__ tf, float* __restrict__ tn,
                               float* __restrict__ tn256,
                               unsigned short* __restrict__ tfbx) {
  int gid = blockIdx.x * blockDim.x + threadIdx.x;
  int w = gid >> 6;
  int lane = gid & 63;
  if (w >= TPAD) return;
  unsigned short* base = tfbx + (size_t)w * 128;
  int jj = lane >> 2;
  int soff = ((jj ^ (w & 7)) << 3) + (lane & 3) * 2;
  if (w < TT) {
    const float* p = tf + (size_t)w * FE;
    float a = p[lane];
    float b = p[lane + 64];
    float s = a * a + b * b;
#pragma unroll
    for (int off = 32; off > 0; off >>= 1) s += __shfl_xor(s, off);
    if (lane == 0) { tn[w] = s; tn256[w] = s + 256.0f; }
    ushort2 o;
    o.x = f2bf(p[2 * lane]);
    o.y = f2bf(p[2 * lane + 1]);
    *reinterpret_cast<ushort2*>(base + soff) = o;
  } else {
    if (lane == 0) { tn[w] = 1e30f; tn256[w] = 3e38f; }  // pads never win
    ushort2 z; z.x = 0; z.y = 0;
    *reinterpret_cast<ushort2*>(base + soff) = z;
  }
}

// ---------------- K1: 32x32x16-MFMA, 160-row stationary, 5 lists/lane ----------------
// Block = 160 rows (LDS once) x 1792 cols (14 strips x 128). Wave wv owns cols
// wv*32..+31 of each strip. MFMA 32x32x16: A = 32 target cols (D-row = tcol),
// B = 32 source rows (D-col = srow = lane&31) -> lane sees 5 srows -> kq[5][6]
// packed keys in VGPRs. C-layout: row=(r&3)+8*(r>>2)+4*(lane>>5), col=lane&31.
// key = (bits(tn+256-2dp) & ~0x1FFF) | col (metric > 0 => uint order == float).
union SmemK1 {
  struct {
    unsigned short Bs[RPB * 128];   // 40960 B stationary source rows
    unsigned short As[128 * 128];   // 32768 B strip tile
  } m;
  struct {
    uint pkb[RPB][25];              // 24 wave-candidates + pad (epilogue overlay)
  } e;
};

__global__ __launch_bounds__(256, 2) void topk_kernel(
    const float* __restrict__ sf, const unsigned short* __restrict__ tfbx,
    const float* __restrict__ tn256, uint* __restrict__ pkall) {
  __shared__ SmemK1 u;
  const int tid = threadIdx.x;
  const int lane = tid & 63;
  const int wv = tid >> 6;
  const int hh = lane >> 5;          // k-half
  const int l5 = lane & 31;
  const int rb = (int)blockIdx.x >> 2;
  const int cb = (int)blockIdx.x & 3;
  const int row0 = rb * RPB;         // exact: 125*160 = 20000
  const int cbase = cb * CBW;

  // one-time stage: source rows -> Bs (bf16, swizzled; writes 8-way spread)
  if (tid < RPB) {
    const float* src = sf + (size_t)(row0 + tid) * FE;
    unsigned short* dst = u.m.Bs + tid * 128;
    const int sw = tid & 7;
#pragma unroll
    for (int jj = 0; jj < 16; ++jj) {
      float4 f0 = *reinterpret_cast<const float4*>(src + jj * 8);
      float4 f1 = *reinterpret_cast<const float4*>(src + jj * 8 + 4);
      union { unsigned short us[8]; uint4 v; } t;
      t.us[0] = f2bf(f0.x); t.us[1] = f2bf(f0.y);
      t.us[2] = f2bf(f0.z); t.us[3] = f2bf(f0.w);
      t.us[4] = f2bf(f1.x); t.us[5] = f2bf(f1.y);
      t.us[6] = f2bf(f1.z); t.us[7] = f2bf(f1.w);
      *reinterpret_cast<uint4*>(dst + ((jj ^ sw) << 3)) = t.v;
    }
  }

  uint kq[5][6];
#pragma unroll
  for (int h = 0; h < 5; ++h)
#pragma unroll
    for (int k = 0; k < 6; ++k) kq[h][k] = 0xFFFFFFFFu;

  // swizzled chunk offsets (shorts): ((2ks+hh) ^ (lane&7)) * 8
  int chsw[8];
#pragma unroll
  for (int ks = 0; ks < 8; ++ks) chsw[ks] = (((2 * ks + hh) ^ (lane & 7)) << 3);
  const int abase = l5 * 128;        // A row base (col l5 of wave's 32)

  __syncthreads();

  for (int s = 0; s < NSTRIP; ++s) {
    // stage A tile 32KB: linear tid*16-byte copy -> conflict-free writes
    {
      const char* g = reinterpret_cast<const char*>(tfbx) +
                      (size_t)(cbase + s * 128) * 256 + tid * 16;
      char* d = reinterpret_cast<char*>(u.m.As) + tid * 16;
#pragma unroll
      for (int i = 0; i < 8; ++i) {
        uint4 v = *reinterpret_cast<const uint4*>(g + i * 4096);
        *reinterpret_cast<uint4*>(d + i * 4096) = v;
      }
    }
    __syncthreads();

    const int colq = cbase + s * 128 + wv * 32 + 4 * hh;  // col of reg r: +8*(r>>2)+(r&3)
    union { float4 v[4]; float f[16]; } tnf;
#pragma unroll
    for (int t4 = 0; t4 < 4; ++t4)
      tnf.v[t4] = *reinterpret_cast<const float4*>(tn256 + colq + t4 * 8);
    uint cbr[16];
#pragma unroll
    for (int r = 0; r < 16; ++r) cbr[r] = (uint)(colq + ((r >> 2) << 3) + (r & 3));

    // A-frags stationary for the strip
    const unsigned short* ab = u.m.As + (wv * 32 + l5) * 128;
    short8 af[8];
#pragma unroll
    for (int ks = 0; ks < 8; ++ks)
      af[ks] = *reinterpret_cast<const short8*>(ab + chsw[ks]);

#pragma unroll
    for (int h = 0; h < 5; ++h) {
      const unsigned short* bb = u.m.Bs + (h * 32 + l5) * 128;
      floatx16 acc;
#pragma unroll
      for (int r = 0; r < 16; ++r) acc[r] = 0.f;
#pragma unroll
      for (int ks = 0; ks < 8; ++ks) {
        short8 b = *reinterpret_cast<const short8*>(bb + chsw[ks]);
        acc = __builtin_amdgcn_mfma_f32_32x32x16_bf16(af[ks], b, acc, 0, 0, 0);
      }
#pragma unroll
      for (int r = 0; r < 16; ++r) {
        float met = fmaf(-2.f, acc[r], tnf.f[r]);            // > 0 always
        uint t = (__float_as_uint(met) & 0xFFFFE000u) | cbr[r];
#pragma unroll
        for (int k = 0; k < 6; ++k) {                         // branchless insert
          uint lo = min(kq[h][k], t);
          uint hi = max(kq[h][k], t);
          kq[h][k] = lo;
          t = hi;
        }
      }
    }
    __syncthreads();   // all reads done before next strip overwrites As
  }

  // lane <-> lane+32 merge per srow (disjoint tcol substreams, both sorted):
  // smallest-6 of two sorted-6 = elementwise min(a[i], b[5-i])
#pragma unroll
  for (int h = 0; h < 5; ++h) {
    uint pr[6];
#pragma unroll
    for (int k = 0; k < 6; ++k) pr[k] = __shfl_xor(kq[h][k], 32);
#pragma unroll
    for (int k = 0; k < 6; ++k) kq[h][k] = min(kq[h][k], pr[5 - k]);
  }
  __syncthreads();   // tiles dead; overlay epilogue
  if (lane < 32) {
#pragma unroll
    for (int h = 0; h < 5; ++h)
#pragma unroll
      for (int k = 0; k < 6; ++k) u.e.pkb[h * 32 + lane][wv * 6 + k] = kq[h][k];
  }
  __syncthreads();

  // per row: top-8 of the 24 wave-candidates -> pkall[row][cb*8..]
  if (tid < RPB) {
    uint md[8];
#pragma unroll
    for (int k = 0; k < 8; ++k) md[k] = 0xFFFFFFFFu;
    for (int j = 0; j < 24; ++j) {
      uint t = u.e.pkb[tid][j];
#pragma unroll
      for (int k = 0; k < 8; ++k) {
        uint lo = min(md[k], t);
        uint hi = max(md[k], t);
        md[k] = lo;
        t = hi;
      }
    }
    uint* dst = pkall + (size_t)(row0 + tid) * 32 + cb * 8;
#pragma unroll
    for (int k = 0; k < 8; ++k) dst[k] = md[k];
  }
}

// ---------------- K1b: rescore 32 candidates/row in fp32, top-6, pred ----------------
__global__ __launch_bounds__(256) void merge_kernel(
    const float* __restrict__ sf, const float* __restrict__ tf,
    const float* __restrict__ tn, const uint* __restrict__ pkall,
    const float* __restrict__ tp, float* __restrict__ pred) {
  __shared__ float sv[4][33];
  __shared__ int   scc[4][33];
  const int lane = threadIdx.x & 63;
  const int w = threadIdx.x >> 6;
  const int row = (int)blockIdx.x * 4 + w;    // exact: 5000*4 = 20000
  const int cand = lane >> 1, half = lane & 1;
  uint key = pkall[(size_t)row * 32 + cand];
  int col = (int)(key & 0x1FFFu);
  const float* sr = sf + (size_t)row * FE + half * 64;
  const float* tr = tf + (size_t)col * FE + half * 64;
  float a = 0.f;
#pragma unroll 16
  for (int kk = 0; kk < 64; kk += 4) {
    float4 av = *reinterpret_cast<const float4*>(sr + kk);
    float4 bv = *reinterpret_cast<const float4*>(tr + kk);
    a += av.x * bv.x + av.y * bv.y + av.z * bv.z + av.w * bv.w;
  }
  a += __shfl_xor(a, 1);
  if (half == 0) { sv[w][cand] = tn[col] - 2.f * a; scc[w][cand] = col; }
  __syncthreads();
  if (lane == 0) {
    float sd[6]; int sp6[6];
#pragma unroll
    for (int k = 0; k < 6; ++k) { sd[k] = 1e30f; sp6[k] = 0; }
    for (int j = 0; j < 32; ++j) {
      float v = sv[w][j];
      if (v < sd[5]) {
        sd[5] = v; sp6[5] = j;
#pragma unroll
        for (int k = 4; k >= 0; --k) {
          if (sd[k + 1] < sd[k]) {
            float tvv = sd[k]; sd[k] = sd[k + 1]; sd[k + 1] = tvv;
            int tii = sp6[k]; sp6[k] = sp6[k + 1]; sp6[k + 1] = tii;
          }
        }
      }
    }
    float wgt[6]; float wsum = 0.f;
#pragma unroll
    for (int k = 0; k < 6; ++k) { wgt[k] = __expf(sd[0] - sd[k]); wsum += wgt[k]; }
    float inv = 1.f / wsum;
    float px = 0.f, py = 0.f, pz = 0.f;
#pragma unroll
    for (int k = 0; k < 6; ++k) {
      float scv = wgt[k] * inv;
      const float* qq = tp + (size_t)scc[w][sp6[k]] * 3;
      px += scv * qq[0]; py += scv * qq[1]; pz += scv * qq[2];
    }
    pred[row * 3 + 0] = px;
    pred[row * 3 + 1] = py;
    pred[row * 3 + 2] = pz;
  }
}

// ---------------- K2: per-node Procrustes (3x3 SVD, fp64 Jacobi) ----------------
__global__ __launch_bounds__(64) void proc_kernel(
    const int* __restrict__ colp, const float* __restrict__ pos,
    const float* __restrict__ pred, float* __restrict__ Rout,
    float* __restrict__ tout, float* __restrict__ qnorm) {
  int i = blockIdx.x * blockDim.x + threadIdx.x;
  if (i >= NS) return;
  int4 cia[8];
#pragma unroll
  for (int t = 0; t < 8; ++t)
    cia[t] = reinterpret_cast<const int4*>(colp + (size_t)i * DEG)[t];
  const int* cidx = reinterpret_cast<const int*>(cia);

  double sp[3] = {0, 0, 0}, sq[3] = {0, 0, 0};
  double spq[3][3] = {{0, 0, 0}, {0, 0, 0}, {0, 0, 0}};
#pragma unroll
  for (int e = 0; e < DEG; ++e) {
    int c = cidx[e];
    double p0 = pos[c * 3], p1 = pos[c * 3 + 1], p2 = pos[c * 3 + 2];
    double q0 = pred[c * 3], q1 = pred[c * 3 + 1], q2 = pred[c * 3 + 2];
    sp[0] += p0; sp[1] += p1; sp[2] += p2;
    sq[0] += q0; sq[1] += q1; sq[2] += q2;
    spq[0][0] += p0 * q0; spq[0][1] += p0 * q1; spq[0][2] += p0 * q2;
    spq[1][0] += p1 * q0; spq[1][1] += p1 * q1; spq[1][2] += p1 * q2;
    spq[2][0] += p2 * q0; spq[2][1] += p2 * q1; spq[2][2] += p2 * q2;
  }
  const double inv = 1.0 / 32.0;
  double A[3][3], sc[3], tcn[3];
  for (int a = 0; a < 3; ++a) {
    sc[a] = sp[a] * inv;
    tcn[a] = sq[a] * inv;
  }
  for (int a = 0; a < 3; ++a)
    for (int b = 0; b < 3; ++b) A[a][b] = spq[a][b] - sp[a] * sq[b] * inv;

  double S[3][3];
  for (int a = 0; a < 3; ++a)
    for (int b = 0; b < 3; ++b)
      S[a][b] = A[0][a] * A[0][b] + A[1][a] * A[1][b] + A[2][a] * A[2][b];
  double V[3][3] = {{1, 0, 0}, {0, 1, 0}, {0, 0, 1}};
  const int JP[3] = {0, 0, 1}, JQ[3] = {1, 2, 2};
  for (int sweep = 0; sweep < 6; ++sweep) {
    for (int r = 0; r < 3; ++r) {
      int p = JP[r], q = JQ[r];
      double apq = S[p][q];
      if (fabs(apq) < 1e-300) continue;
      double theta = (S[q][q] - S[p][p]) / (2.0 * apq);
      double t = copysign(1.0 / (fabs(theta) + sqrt(theta * theta + 1.0)), theta);
      double c = 1.0 / sqrt(t * t + 1.0);
      double s = t * c;
      double spp = S[p][p], sqq = S[q][q];
      S[p][p] = spp - t * apq;
      S[q][q] = sqq + t * apq;
      S[p][q] = 0.0; S[q][p] = 0.0;
      int k = 3 - p - q;
      double skp = S[k][p], skq = S[k][q];
      S[k][p] = S[p][k] = c * skp - s * skq;
      S[k][q] = S[q][k] = s * skp + c * skq;
      for (int mth = 0; mth < 3; ++mth) {
        double vp = V[mth][p], vq = V[mth][q];
        V[mth][p] = c * vp - s * vq;
        V[mth][q] = s * vp + c * vq;
      }
    }
  }
  double lam[3] = {S[0][0], S[1][1], S[2][2]};
  int i0 = 0, i1 = 1, i2 = 2, tmp;
  if (lam[i0] < lam[i1]) { tmp = i0; i0 = i1; i1 = tmp; }
  if (lam[i0] < lam[i2]) { tmp = i0; i0 = i2; i2 = tmp; }
  if (lam[i1] < lam[i2]) { tmp = i1; i1 = i2; i2 = tmp; }
  double v0[3] = {V[0][i0], V[1][i0], V[2][i0]};
  double v1[3] = {V[0][i1], V[1][i1], V[2][i1]};
  double v2[3] = {V[0][i2], V[1][i2], V[2][i2]};

  double Av0[3], Av1[3], Av2[3];
  for (int a = 0; a < 3; ++a) {
    Av0[a] = A[a][0] * v0[0] + A[a][1] * v0[1] + A[a][2] * v0[2];
    Av1[a] = A[a][0] * v1[0] + A[a][1] * v1[1] + A[a][2] * v1[2];
    Av2[a] = A[a][0] * v2[0] + A[a][1] * v2[1] + A[a][2] * v2[2];
  }
  double n0 = fmax(sqrt(Av0[0]*Av0[0] + Av0[1]*Av0[1] + Av0[2]*Av0[2]), 1e-300);
  double u0[3] = {Av0[0] / n0, Av0[1] / n0, Av0[2] / n0};
  double proj = u0[0]*Av1[0] + u0[1]*Av1[1] + u0[2]*Av1[2];
  double u1[3] = {Av1[0] - proj * u0[0], Av1[1] - proj * u0[1], Av1[2] - proj * u0[2]};
  double n1 = fmax(sqrt(u1[0]*u1[0] + u1[1]*u1[1] + u1[2]*u1[2]), 1e-300);
  u1[0] /= n1; u1[1] /= n1; u1[2] /= n1;
  double w[3] = {u0[1]*u1[2] - u0[2]*u1[1],
                 u0[2]*u1[0] - u0[0]*u1[2],
                 u0[0]*u1[1] - u0[1]*u1[0]};
  double dotw = Av2[0]*w[0] + Av2[1]*w[1] + Av2[2]*w[2];
  double sgn = (dotw < 0.0) ? -1.0 : 1.0;
  double detA = A[0][0]*(A[1][1]*A[2][2] - A[1][2]*A[2][1])
              - A[0][1]*(A[1][0]*A[2][2] - A[1][2]*A[2][0])
              + A[0][2]*(A[1][0]*A[2][1] - A[1][1]*A[2][0]);
  double d3 = ((detA < 0.0) ? -1.0 : 1.0) * sgn;

  double R[3][3];
  for (int a = 0; a < 3; ++a)
    for (int b = 0; b < 3; ++b)
      R[a][b] = u0[a]*v0[b] + u1[a]*v1[b] + d3 * w[a]*v2[b];

  for (int a = 0; a < 3; ++a)
    for (int b = 0; b < 3; ++b) Rout[i * 9 + a * 3 + b] = (float)R[a][b];
  double tr_[3];
  for (int a = 0; a < 3; ++a) {
    tr_[a] = tcn[a] - (R[a][0]*sc[0] + R[a][1]*sc[1] + R[a][2]*sc[2]);
    tout[i * 3 + a] = (float)tr_[a];
  }
  double pxi = pos[i * 3], pyi = pos[i * 3 + 1], pzi = pos[i * 3 + 2];
  double r0 = R[0][0]*pxi + R[0][1]*pyi + R[0][2]*pzi + tr_[0] - pred[i * 3];
  double r1 = R[1][0]*pxi + R[1][1]*pyi + R[1][2]*pzi + tr_[1] - pred[i * 3 + 1];
  double r2 = R[2][0]*pxi + R[2][1]*pyi + R[2][2]*pzi + tr_[2] - pred[i * 3 + 2];
  qnorm[i] = (float)(r0 * r0 + r1 * r1 + r2 * r2);
}

// ---------------- K3: per-node residual mean over neighbors ----------------
__global__ __launch_bounds__(64) void dst_kernel(
    const int* __restrict__ colp, const float* __restrict__ qn,
    float* __restrict__ dout) {
  int i = blockIdx.x * blockDim.x + threadIdx.x;
  if (i >= NS) return;
  int4 cia[8];
#pragma unroll
  for (int t = 0; t < 8; ++t)
    cia[t] = reinterpret_cast<const int4*>(colp + (size_t)i * DEG)[t];
  const int* cidx = reinterpret_cast<const int*>(cia);
  float s = 0.f;
#pragma unroll
  for (int e = 0; e < DEG; ++e) s += qn[cidx[e]];
  dout[i] = s * (1.0f / 32.0f);
}

extern "C" void kernel_launch(void* const* d_in, const int* in_sizes, int n_in,
                              void* d_out, int out_size, void* d_ws, size_t ws_size,
                              hipStream_t stream) {
  const float* sf  = (const float*)d_in[0];   // [N,128]
  const float* tf  = (const float*)d_in[1];   // [T,128]
  const float* tp  = (const float*)d_in[2];   // [T,3]
  const float* pos = (const float*)d_in[3];   // [N,3]
  const int*   ei  = (const int*)d_in[4];     // [2,E]
  float* out = (float*)d_out;                 // [N*9 | N*3 | N]
  char* ws = (char*)d_ws;
  // ws layout (~4.7 MB; qn aliases tfbx which is dead after topk):
  float*          tn    = (float*)(ws);                    // 28,672 B
  float*          tn256 = (float*)(ws + 28672);            // 28,672 B
  float*          pred  = (float*)(ws + 57344);            // 240,000 B
  uint*           pkall = (uint*)(ws + 297344);            // 20000*32*4 = 2,560,000 B
  unsigned short* tfbx  = (unsigned short*)(ws + 2857344); // 7168*256 = 1,835,008 B
  float*          qn    = (float*)(ws + 2857344);          // alias (post-topk)
  const int* colp = ei + EDG;

  tn_cast_kernel<<<(TPAD * 64) / 256, 256, 0, stream>>>(tf, tn, tn256, tfbx);
  topk_kernel<<<(NS / RPB) * NCB, 256, 0, stream>>>(sf, tfbx, tn256, pkall);
  merge_kernel<<<NS / 4, 256, 0, stream>>>(sf, tf, tn, pkall, tp, pred);
  proc_kernel<<<(NS + 63) / 64, 64, 0, stream>>>(colp, pos, pred, out,
                                                 out + NS * 9, qn);
  dst_kernel<<<(NS + 63) / 64, 64, 0, stream>>>(colp, qn, out + NS * 12);
}